// Round 1
// 203.652 us; speedup vs baseline: 1.0390x; 1.0390x over previous
//
#include <hip/hip_runtime.h>
#include <hip/hip_bf16.h>

#define N_GRAPHS 200
#define NPG      500
#define NPGP     512                   // padded nodes per graph (MFMA tiles)
#define N_NODES_ 100000
#define N_EDGES_ 1600000
#define DIN      64
#define DG       128
#define SEQ      20
#define HL       128
#define G4       512
#define BWIN     (N_GRAPHS - SEQ + 1)  // 181
#define NPART    512
#define EPB      (N_EDGES_/NPART)      // 3125
#define SLOTS    48                    // LDS bucket slots/graph/block (mean 15.6 + 8.2 sigma)
#define CAP      9216                  // per-graph edge segment capacity

typedef __attribute__((ext_vector_type(8))) short short8;
typedef __attribute__((ext_vector_type(4))) float float4v;
typedef __attribute__((ext_vector_type(2))) _Float16 half2v;

__device__ __forceinline__ float sigmoidf_(float v){ return 1.0f/(1.0f+expf(-v)); }

// fp32 -> bf16 round-to-nearest-even
__device__ __forceinline__ unsigned short f2bf(float f) {
  unsigned int u = __float_as_uint(f);
  u += 0x7fffu + ((u >> 16) & 1u);
  return (unsigned short)(u >> 16);
}

__device__ __forceinline__ float h2dot(half2v a, half2v b, float c) {
#if __has_builtin(__builtin_amdgcn_fdot2)
  return __builtin_amdgcn_fdot2(a, b, c, false);
#else
  return c + (float)a.x*(float)b.x + (float)a.y*(float)b.y;
#endif
}

// K1: scan-free partition into contiguous per-graph segments part[g*CAP ...].
// LDS bucket (48 slots/graph) -> one device atomicAdd per (block,graph) to
// reserve a base -> wave-per-graph coalesced flush. 512 blocks.
__global__ __launch_bounds__(256) void k_part(const int* __restrict__ src,
                                              const int* __restrict__ dst,
                                              int* __restrict__ gcount,
                                              int* __restrict__ part) {
  __shared__ int cnt[N_GRAPHS];
  __shared__ int base[N_GRAPHS];
  __shared__ int buf[N_GRAPHS][SLOTS];   // 38.4 KB
  int b = blockIdx.x, t = threadIdx.x;
  for (int g = t; g < N_GRAPHS; g += 256) cnt[g] = 0;
  __syncthreads();
  int e0 = b*EPB;
  for (int i = t; i < EPB; i += 256) {
    int s = src[e0+i], d = dst[e0+i];
    int g = s / NPG;
    int sl = s - g*NPG, dl = d - g*NPG;
    int pk = (sl << 9) | dl;
    int pos = atomicAdd(&cnt[g], 1);
    if (pos < SLOTS) buf[g][pos] = pk;
    else {                                // rare overflow (>8 sigma)
      int gp = atomicAdd(&gcount[g], 1);
      part[g*CAP + gp] = pk;
    }
  }
  __syncthreads();
  if (t < N_GRAPHS) base[t] = atomicAdd(&gcount[t], min(cnt[t], SLOTS));
  __syncthreads();
  int w = t >> 6, lane = t & 63;
  for (int g = w; g < N_GRAPHS; g += 4) {
    int n = min(cnt[g], SLOTS);
    int ba = g*CAP + base[g];
    if (lane < n) part[ba + lane] = buf[g][lane];   // n <= 48 < 64: one pass
  }
}

// K2: per-graph counting sort (dense contiguous segment) -> sorted src list +
// node metadata + fused xprep (xsb = bf16(x*so)).
// Round-change: edge segment cached in LDS (pass 2 no longer re-reads 6.4 MB
// from global); Hillis-Steele 9-sync scan replaced by wave-shfl scan (3 syncs).
__global__ __launch_bounds__(512) void k_sort(const int* __restrict__ gcount,
    const int* __restrict__ part, const float* __restrict__ x,
    unsigned short* __restrict__ sorted_all,
    int* __restrict__ e_end, int* __restrict__ e_deg,
    ushort4* __restrict__ xsb) {
  __shared__ int indeg[NPG], outdeg[NPG], off[NPG];
  __shared__ float soS[NPG];
  __shared__ int wsum[8];
  __shared__ int eC[CAP];                // 36.9 KB edge cache
  int g = blockIdx.x, t = threadIdx.x;
  int seg0 = g*CAP;
  int nseg = gcount[g];
  if (t < NPG) { indeg[t] = 0; outdeg[t] = 0; }
  __syncthreads();
  for (int e = t; e < nseg; e += 512) {
    int p = part[seg0 + e];
    eC[e] = p;
    atomicAdd(&indeg[p & 511], 1);
    atomicAdd(&outdeg[p >> 9], 1);
  }
  __syncthreads();
  int lane = t & 63, w = t >> 6;
  int v = (t < NPG) ? indeg[t] : 0;
  int s = v;
  #pragma unroll
  for (int o = 1; o < 64; o <<= 1) { int n = __shfl_up(s, o); if (lane >= o) s += n; }
  if (lane == 63) wsum[w] = s;
  __syncthreads();
  int woff = 0;
  #pragma unroll
  for (int i = 0; i < 8; ++i) woff += (i < w) ? wsum[i] : 0;
  if (t < NPG) {
    off[t] = woff + s - v;               // exclusive prefix
    soS[t] = rsqrtf((float)max(outdeg[t], 1));
    e_deg[g*NPG + t] = v;
  }
  __syncthreads();
  for (int e = t; e < nseg; e += 512) {
    int p = eC[e];
    int pos = atomicAdd(&off[p & 511], 1);
    sorted_all[seg0 + pos] = (unsigned short)(p >> 9);
  }
  __syncthreads();
  if (t < NPG) e_end[g*NPG + t] = seg0 + off[t];   // inclusive end
  __syncthreads();
  // fused xprep
  const float4* xg = ((const float4*)x) + (size_t)g*8000;   // 500*16
  ushort4* og = xsb + (size_t)g*8000;
  for (int i = t; i < 8000; i += 512) {
    float4 vv = xg[i];
    float s2 = soS[i >> 4];
    ushort4 u;
    u.x = f2bf(vv.x*s2); u.y = f2bf(vv.y*s2); u.z = f2bf(vv.z*s2); u.w = f2bf(vv.w*s2);
    og[i] = u;
  }
}

// K3: aggregation v5 — whole 64 KB xsb slice in LDS plus a zero row (500).
// Round-change vs v4: (a) 2 blocks/graph (400 blocks, all resident at
// 2 blocks/CU -> no second dispatch round, staging traffic halved),
// (b) each 8-lane group owns FOUR nodes (better degree-imbalance averaging),
// (c) edges consumed in chunks of 8: one coalesced 2B load per lane +
// __shfl group-broadcast; tail padded by zero-row index 500 -> branch-free
// inner body the compiler can software-pipeline (removes the serial
// global-load -> ds_read dependency chain of v4).
__global__ __launch_bounds__(512) void k_agg(const int4* __restrict__ xsb,
    const int* __restrict__ e_end, const int* __restrict__ e_deg,
    const unsigned short* __restrict__ sorted_all,
    unsigned short* __restrict__ hpreb) {
  __shared__ int4 xLds[4008];            // 500 rows x 8 int4 + zero row
  int b = blockIdx.x;
  int xcd = b & 7, q = b >> 3;           // q 0..49
  int g = xcd*25 + (q >> 1);             // graph; 2 blocks/graph on one XCD
  int p = q & 1;                         // half: node slots p*256 .. p*256+255
  int t = threadIdx.x;
  const int4* xg = xsb + (size_t)g*4000;
  for (int i = t; i < 4000; i += 512) xLds[i] = xg[i];
  if (t < 8) xLds[4000 + t] = make_int4(0,0,0,0);
  __syncthreads();
  int w8 = t >> 6, lane = t & 63, g8 = lane >> 3, fl = lane & 7;
  #pragma unroll
  for (int s0 = 0; s0 < 32; s0 += 8) {
    int nl = p*256 + w8*32 + s0 + g8;
    int npad = g*NPGP + nl;
    if (nl >= NPG) {                     // pad rows -> zeros
      ((int4*)hpreb)[(size_t)npad*8 + fl] = make_int4(0,0,0,0);
      continue;
    }
    int n = g*NPG + nl;
    int end = e_end[n], deg = e_deg[n], start = end - deg;
    float aHi[4] = {0.f,0.f,0.f,0.f};
    float aLo[4] = {0.f,0.f,0.f,0.f};
    for (int c0 = 0; c0 < deg; c0 += 8) {
      int ev = 500;                       // zero row
      if (c0 + fl < deg) ev = (int)sorted_all[start + c0 + fl];
      #pragma unroll
      for (int j = 0; j < 8; ++j) {
        int se = __shfl(ev, (g8 << 3) + j);
        int4 v = xLds[(se << 3) + fl];
        aHi[0] += __uint_as_float((unsigned)v.x & 0xffff0000u);
        aLo[0] += __uint_as_float((unsigned)v.x << 16);
        aHi[1] += __uint_as_float((unsigned)v.y & 0xffff0000u);
        aLo[1] += __uint_as_float((unsigned)v.y << 16);
        aHi[2] += __uint_as_float((unsigned)v.z & 0xffff0000u);
        aLo[2] += __uint_as_float((unsigned)v.z << 16);
        aHi[3] += __uint_as_float((unsigned)v.w & 0xffff0000u);
        aLo[3] += __uint_as_float((unsigned)v.w << 16);
      }
    }
    float sn = rsqrtf((float)max(deg, 1));
    int4 outv;
    outv.x = (int)(((unsigned)f2bf(aLo[0]*sn)) | ((unsigned)f2bf(aHi[0]*sn) << 16));
    outv.y = (int)(((unsigned)f2bf(aLo[1]*sn)) | ((unsigned)f2bf(aHi[1]*sn) << 16));
    outv.z = (int)(((unsigned)f2bf(aLo[2]*sn)) | ((unsigned)f2bf(aHi[2]*sn) << 16));
    outv.w = (int)(((unsigned)f2bf(aLo[3]*sn)) | ((unsigned)f2bf(aHi[3]*sn) << 16));
    ((int4*)hpreb)[(size_t)npad*8 + fl] = outv;
  }
}

// K4: MFMA GCN GEMM + ReLU + mean pool + fused input projection.
// Also converts w_hh -> fp16 global (whh16) spread over 200 blocks.
// Round-change: w_gcn staged with coalesced float4 reads (was 32 stride-512B
// scalar reads per thread).
__global__ __launch_bounds__(256) void k_gcn(
    const unsigned short* __restrict__ hpreb,
    const float* __restrict__ w_gcn,
    const float* __restrict__ b_gcn,
    const float* __restrict__ w_ih,
    const float* __restrict__ b_ih,
    const float* __restrict__ w_hh,
    int4* __restrict__ whh16,
    float* __restrict__ proj) {
  __shared__ unsigned short wLds[16*64*8];   // 16 KB
  __shared__ float pS[4*DG];
  __shared__ __align__(16) float hgS[DG];
  int t = threadIdx.x, g = blockIdx.x;
  // w_hh fp32 -> fp16 conversion slice (layout: i = k4*512 + r)
  for (int i = g*256 + t; i < 8192; i += N_GRAPHS*256) {
    int k4 = i >> 9, r = i & 511;
    const float4* wp = (const float4*)(w_hh + (size_t)r*HL + k4*8);
    float4 w0 = wp[0], w1 = wp[1];
    half2v p0 = {(_Float16)w0.x, (_Float16)w0.y};
    half2v p1 = {(_Float16)w0.z, (_Float16)w0.w};
    half2v p2 = {(_Float16)w1.x, (_Float16)w1.y};
    half2v p3 = {(_Float16)w1.z, (_Float16)w1.w};
    int4 pk;
    pk.x = __builtin_bit_cast(int, p0); pk.y = __builtin_bit_cast(int, p1);
    pk.z = __builtin_bit_cast(int, p2); pk.w = __builtin_bit_cast(int, p3);
    whh16[i] = pk;
  }
  // coalesced w_gcn staging: 2048 float4s (64 rows x 32 float4)
  for (int i = t; i < 2048; i += 256) {
    float4 w4 = ((const float4*)w_gcn)[i];
    int k = i >> 5;                      // global k row 0..63
    int c4 = (i & 31) << 2;              // col base
    int h = k >> 5;                      // 0/1
    int j = k & 7;
    int lhi = ((k >> 3) & 3) << 4;       // (l>>4)*16
    float vv[4] = {w4.x, w4.y, w4.z, w4.w};
    #pragma unroll
    for (int u = 0; u < 4; ++u) {
      int n = c4 + u;
      int idx = ((n >> 4)*2 + h)*64 + lhi + (n & 15);
      wLds[idx*8 + j] = f2bf(vv[u]);
    }
  }
  __syncthreads();
  int w = t >> 6, lane = t & 63;
  int quad = lane >> 4, l15 = lane & 15;
  float bcol[8];
  #pragma unroll
  for (int nt = 0; nt < 8; ++nt) bcol[nt] = b_gcn[nt*16 + l15];
  float psum[8] = {0.f,0.f,0.f,0.f,0.f,0.f,0.f,0.f};
  const unsigned short* hb = hpreb + (size_t)g*NPGP*DIN;
  for (int i = 0; i < 8; ++i) {
    int rt = w + 4*i;
    int row0 = rt*16;
    const short8* aptr = (const short8*)(hb + (size_t)(row0 + l15)*DIN + quad*8);
    short8 a0 = aptr[0];
    short8 a1 = aptr[4];
    #pragma unroll
    for (int nt = 0; nt < 8; ++nt) {
      short8 b0 = *((const short8*)&wLds[((nt*2+0)*64 + lane)*8]);
      short8 b1 = *((const short8*)&wLds[((nt*2+1)*64 + lane)*8]);
      float4v acc = {0.f, 0.f, 0.f, 0.f};
      acc = __builtin_amdgcn_mfma_f32_16x16x32_bf16(a0, b0, acc, 0, 0, 0);
      acc = __builtin_amdgcn_mfma_f32_16x16x32_bf16(a1, b1, acc, 0, 0, 0);
      #pragma unroll
      for (int r = 0; r < 4; ++r) {
        int node = row0 + quad*4 + r;
        float vvv = acc[r] + bcol[nt];
        psum[nt] += (node < NPG) ? fmaxf(vvv, 0.f) : 0.f;
      }
    }
  }
  #pragma unroll
  for (int nt = 0; nt < 8; ++nt) {
    float vvv = psum[nt];
    vvv += __shfl_xor(vvv, 16);
    vvv += __shfl_xor(vvv, 32);
    if (lane < 16) pS[w*DG + nt*16 + lane] = vvv;
  }
  __syncthreads();
  if (t < DG)
    hgS[t] = (pS[t] + pS[DG+t] + pS[2*DG+t] + pS[3*DG+t]) * (1.0f/NPG);
  __syncthreads();
  for (int r = t; r < G4; r += 256) {
    const float4* wr = (const float4*)(w_ih + (size_t)r*HL);
    const float4* hv = (const float4*)hgS;
    float acc = b_ih[r];
    #pragma unroll
    for (int k4 = 0; k4 < 32; ++k4) {
      float4 w4 = wr[k4]; float4 h4 = hv[k4];
      acc += w4.x*h4.x + w4.y*h4.y + w4.z*h4.z + w4.w*h4.w;
    }
    proj[(size_t)g*G4 + r] = acc;
  }
}

// K5: LSTM — w_hh fp16 CU-resident in LDS; h packed fp16; fp32 accumulation
// via v_dot2_f32_f16. Round-change: gemv accumulation split into 4
// independent chains (was one 64-deep dependent fdot2 chain).
__global__ __launch_bounds__(512) void k_lstm(const float* __restrict__ proj,
    const int4* __restrict__ whh16, const float* __restrict__ b_hh,
    const float* __restrict__ w_fc, const float* __restrict__ b_fc,
    float* __restrict__ out) {
  __shared__ int4 wL[16*512];        // 128 KB: [k4][r] = 8 fp16 of w_hh[r][k4*8..]
  __shared__ float gS[G4];
  __shared__ __align__(16) int4 hPi[16];  // 128 fp16 packed h state
  int b = blockIdx.x, t = threadIdx.x;
  for (int i = t; i < 16*512; i += 512) wL[i] = whh16[i];
  if (t < 16) hPi[t] = make_int4(0,0,0,0);
  float bh = b_hh[t];
  float c0 = 0.f, c1 = 0.f;
  __syncthreads();
  for (int l = 0; l < SEQ; ++l) {
    float a0 = proj[(size_t)(b+l)*G4 + t] + bh;
    float a1 = 0.f, a2 = 0.f, a3 = 0.f;
    #pragma unroll
    for (int k4 = 0; k4 < 16; k4 += 4) {
      int4 wv0 = wL[((k4+0) << 9) + t]; int4 hv0 = hPi[k4+0];
      int4 wv1 = wL[((k4+1) << 9) + t]; int4 hv1 = hPi[k4+1];
      int4 wv2 = wL[((k4+2) << 9) + t]; int4 hv2 = hPi[k4+2];
      int4 wv3 = wL[((k4+3) << 9) + t]; int4 hv3 = hPi[k4+3];
      a0 = h2dot(__builtin_bit_cast(half2v, wv0.x), __builtin_bit_cast(half2v, hv0.x), a0);
      a0 = h2dot(__builtin_bit_cast(half2v, wv0.y), __builtin_bit_cast(half2v, hv0.y), a0);
      a0 = h2dot(__builtin_bit_cast(half2v, wv0.z), __builtin_bit_cast(half2v, hv0.z), a0);
      a0 = h2dot(__builtin_bit_cast(half2v, wv0.w), __builtin_bit_cast(half2v, hv0.w), a0);
      a1 = h2dot(__builtin_bit_cast(half2v, wv1.x), __builtin_bit_cast(half2v, hv1.x), a1);
      a1 = h2dot(__builtin_bit_cast(half2v, wv1.y), __builtin_bit_cast(half2v, hv1.y), a1);
      a1 = h2dot(__builtin_bit_cast(half2v, wv1.z), __builtin_bit_cast(half2v, hv1.z), a1);
      a1 = h2dot(__builtin_bit_cast(half2v, wv1.w), __builtin_bit_cast(half2v, hv1.w), a1);
      a2 = h2dot(__builtin_bit_cast(half2v, wv2.x), __builtin_bit_cast(half2v, hv2.x), a2);
      a2 = h2dot(__builtin_bit_cast(half2v, wv2.y), __builtin_bit_cast(half2v, hv2.y), a2);
      a2 = h2dot(__builtin_bit_cast(half2v, wv2.z), __builtin_bit_cast(half2v, hv2.z), a2);
      a2 = h2dot(__builtin_bit_cast(half2v, wv2.w), __builtin_bit_cast(half2v, hv2.w), a2);
      a3 = h2dot(__builtin_bit_cast(half2v, wv3.x), __builtin_bit_cast(half2v, hv3.x), a3);
      a3 = h2dot(__builtin_bit_cast(half2v, wv3.y), __builtin_bit_cast(half2v, hv3.y), a3);
      a3 = h2dot(__builtin_bit_cast(half2v, wv3.z), __builtin_bit_cast(half2v, hv3.z), a3);
      a3 = h2dot(__builtin_bit_cast(half2v, wv3.w), __builtin_bit_cast(half2v, hv3.w), a3);
    }
    gS[t] = (a0 + a1) + (a2 + a3);
    __syncthreads();
    if (t < 64) {
      int j0 = 2*t, j1 = 2*t + 1;
      float i0 = sigmoidf_(gS[j0]),      i1 = sigmoidf_(gS[j1]);
      float f0 = sigmoidf_(gS[HL+j0]),   f1 = sigmoidf_(gS[HL+j1]);
      float g0 = tanhf(gS[2*HL+j0]),     g1 = tanhf(gS[2*HL+j1]);
      float o0 = sigmoidf_(gS[3*HL+j0]), o1 = sigmoidf_(gS[3*HL+j1]);
      c0 = f0*c0 + i0*g0;
      c1 = f1*c1 + i1*g1;
      float h0 = o0 * tanhf(c0);
      float h1 = o1 * tanhf(c1);
      half2v hp = {(_Float16)h0, (_Float16)h1};
      ((int*)hPi)[t] = __builtin_bit_cast(int, hp);
      if (l == SEQ-1) {
        float s = h0*w_fc[j0] + h1*w_fc[j1];
        #pragma unroll
        for (int off = 32; off > 0; off >>= 1) s += __shfl_down(s, off);
        if (t == 0) out[b] = s + b_fc[0];
      }
    }
    __syncthreads();
  }
}

extern "C" void kernel_launch(void* const* d_in, const int* in_sizes, int n_in,
                              void* d_out, int out_size, void* d_ws, size_t ws_size,
                              hipStream_t stream) {
  const float* x     = (const float*)d_in[0];
  const int*   src   = (const int*)d_in[1];
  const int*   dst   = (const int*)d_in[2];
  const float* w_gcn = (const float*)d_in[4];
  const float* b_gcn = (const float*)d_in[5];
  const float* w_ih  = (const float*)d_in[6];
  const float* w_hh  = (const float*)d_in[7];
  const float* b_ih  = (const float*)d_in[8];
  const float* b_hh  = (const float*)d_in[9];
  const float* w_fc  = (const float*)d_in[10];
  const float* b_fc  = (const float*)d_in[11];
  float* out = (float*)d_out;

  char* ws = (char*)d_ws;
  size_t off = 0;
  auto alloc = [&](size_t bytes) -> void* {
    void* p = ws + off; off += (bytes + 255) & ~(size_t)255; return p;
  };
  int* gcount  = (int*)alloc((size_t)N_GRAPHS*4);
  int* part    = (int*)alloc((size_t)N_GRAPHS*CAP*4);
  unsigned short* sorted_all = (unsigned short*)alloc((size_t)N_GRAPHS*CAP*2);
  int* e_end   = (int*)alloc((size_t)N_NODES_*4);
  int* e_deg   = (int*)alloc((size_t)N_NODES_*4);
  ushort4* xsb = (ushort4*)alloc((size_t)N_NODES_*DIN*2);
  unsigned short* hpreb = (unsigned short*)alloc((size_t)N_GRAPHS*NPGP*DIN*2);
  int4* whh16  = (int4*)alloc((size_t)8192*16);
  float* proj  = (float*)alloc((size_t)N_GRAPHS*G4*4);
  (void)ws_size; (void)in_sizes; (void)n_in; (void)out_size;

  hipMemsetAsync(gcount, 0, (size_t)N_GRAPHS*4, stream);
  k_part<<<NPART, 256, 0, stream>>>(src, dst, gcount, part);
  k_sort<<<N_GRAPHS, 512, 0, stream>>>(gcount, part, x, sorted_all, e_end, e_deg, xsb);
  k_agg<<<N_GRAPHS*2, 512, 0, stream>>>((const int4*)xsb, e_end, e_deg, sorted_all, hpreb);
  k_gcn<<<N_GRAPHS, 256, 0, stream>>>(hpreb, w_gcn, b_gcn, w_ih, b_ih, w_hh, whh16, proj);
  k_lstm<<<BWIN, 512, 0, stream>>>(proj, whh16, b_hh, w_fc, b_fc, out);
}